// Round 1
// baseline (9563.803 us; speedup 1.0000x reference)
//
#include <hip/hip_runtime.h>
#include <math.h>

#define N 64
#define LDA 65          // +1 pad: column stride 65 -> bank (i + col) % 32, conflict-free-ish
#define SWEEPS 10

__device__ __forceinline__ void get_pair(int r, int k, int& p, int& q) {
    // Circle-method tournament: round r in [0,63), pair k in [0,32)
    if (k == 0) { p = 63; q = r; }
    else {
        p = r + k; if (p >= 63) p -= 63;   // r<63, k<32 -> at most one subtract
        q = r - k; if (q < 0)  q += 63;
    }
}

__global__ __launch_bounds__(256)
void logeig_kernel(const float* __restrict__ P, float* __restrict__ Out) {
    __shared__ float As[N * LDA];
    __shared__ float Us[N * LDA];
    __shared__ float rc[32];
    __shared__ float rs[32];
    __shared__ float lw[N];

    const int t = threadIdx.x;
    const int bid = blockIdx.x;
    const float* A0 = P + (size_t)bid * (N * N);
    float* O = Out + (size_t)bid * (N * N);

    // ---- Load A (coalesced float4), init U = I ----
    const float4* A4 = (const float4*)A0;
    #pragma unroll
    for (int kk = 0; kk < 4; ++kk) {
        int f = t + kk * 256;            // float4 index in [0,1024)
        float4 v = A4[f];
        int e = f * 4;
        int row = e >> 6;
        int col = e & 63;
        float* ap = &As[row * LDA + col];
        ap[0] = v.x; ap[1] = v.y; ap[2] = v.z; ap[3] = v.w;
        float* up = &Us[row * LDA + col];
        up[0] = (col + 0 == row) ? 1.f : 0.f;
        up[1] = (col + 1 == row) ? 1.f : 0.f;
        up[2] = (col + 2 == row) ? 1.f : 0.f;
        up[3] = (col + 3 == row) ? 1.f : 0.f;
    }
    __syncthreads();

    // ---- Jacobi sweeps ----
    for (int sweep = 0; sweep < SWEEPS; ++sweep) {
        for (int r = 0; r < 63; ++r) {
            // Phase 1: rotation params for 32 pairs
            if (t < 32) {
                int p, q; get_pair(r, t, p, q);
                float app = As[p * LDA + p];
                float aqq = As[q * LDA + q];
                float apq = As[p * LDA + q];
                float c = 1.f, s = 0.f;
                if (fabsf(apq) > 1e-30f) {
                    float tau = (aqq - app) / (2.f * apq);
                    float tt = 1.f / (fabsf(tau) + sqrtf(1.f + tau * tau));
                    if (tau < 0.f) tt = -tt;
                    c = rsqrtf(1.f + tt * tt);
                    s = tt * c;
                }
                rc[t] = c; rs[t] = s;
            }
            __syncthreads();

            // Phase 2a: fused 2x2-block update of A (A <- J^T A J), in place.
            // 1024 blocks of 2x2; item v = t + 256*jj; ki = t&31 (const/thread).
            {
                int ki = t & 31;
                int p1, q1; get_pair(r, ki, p1, q1);
                float c1 = rc[ki], s1 = rs[ki];
                #pragma unroll
                for (int jj = 0; jj < 4; ++jj) {
                    int kj = (t >> 5) + 8 * jj;
                    int p2, q2; get_pair(r, kj, p2, q2);
                    float c2 = rc[kj], s2 = rs[kj];
                    float m00 = As[p1 * LDA + p2];
                    float m01 = As[p1 * LDA + q2];
                    float m10 = As[q1 * LDA + p2];
                    float m11 = As[q1 * LDA + q2];
                    // N = M * Rc,  Rc = [[c2, s2], [-s2, c2]]
                    float n00 = c2 * m00 - s2 * m01;
                    float n01 = s2 * m00 + c2 * m01;
                    float n10 = c2 * m10 - s2 * m11;
                    float n11 = s2 * m10 + c2 * m11;
                    // M' = Rr^T * N, Rr^T = [[c1, -s1], [s1, c1]]
                    As[p1 * LDA + p2] = c1 * n00 - s1 * n10;
                    As[p1 * LDA + q2] = c1 * n01 - s1 * n11;
                    As[q1 * LDA + p2] = s1 * n00 + c1 * n10;
                    As[q1 * LDA + q2] = s1 * n01 + c1 * n11;
                }
            }
            // Phase 2b: U <- U * J (column rotations); independent of A.
            {
                int k = t & 31;
                int p, q; get_pair(r, k, p, q);
                float c = rc[k], s = rs[k];
                #pragma unroll
                for (int jj = 0; jj < 8; ++jj) {
                    int i = (t >> 5) + 8 * jj;    // row of U
                    float up = Us[i * LDA + p];
                    float uq = Us[i * LDA + q];
                    Us[i * LDA + p] = c * up - s * uq;
                    Us[i * LDA + q] = s * up + c * uq;
                }
            }
            __syncthreads();
        }
    }

    // ---- log of eigenvalues (diagonal) ----
    if (t < 64) lw[t] = logf(fmaxf(As[t * LDA + t], 1e-30f));
    __syncthreads();

    // ---- X = U diag(lw) U^T ; 4x4 register tile per thread ----
    {
        int ti = t >> 4;
        int tj = t & 15;
        float acc[4][4];
        #pragma unroll
        for (int a = 0; a < 4; ++a)
            #pragma unroll
            for (int b = 0; b < 4; ++b) acc[a][b] = 0.f;

        for (int k = 0; k < N; ++k) {
            float w = lw[k];
            float ui[4], uj[4];
            #pragma unroll
            for (int a = 0; a < 4; ++a) ui[a] = Us[(4 * ti + a) * LDA + k];
            #pragma unroll
            for (int b = 0; b < 4; ++b) uj[b] = Us[(4 * tj + b) * LDA + k] * w;
            #pragma unroll
            for (int a = 0; a < 4; ++a)
                #pragma unroll
                for (int b = 0; b < 4; ++b)
                    acc[a][b] = fmaf(ui[a], uj[b], acc[a][b]);
        }
        #pragma unroll
        for (int a = 0; a < 4; ++a) {
            float4 vout = make_float4(acc[a][0], acc[a][1], acc[a][2], acc[a][3]);
            ((float4*)O)[(4 * ti + a) * 16 + tj] = vout;
        }
    }
}

extern "C" void kernel_launch(void* const* d_in, const int* in_sizes, int n_in,
                              void* d_out, int out_size, void* d_ws, size_t ws_size,
                              hipStream_t stream) {
    const float* P = (const float*)d_in[0];
    float* Out = (float*)d_out;
    int nmat = in_sizes[0] / (N * N);    // 8192
    logeig_kernel<<<dim3(nmat), dim3(256), 0, stream>>>(P, Out);
}

// Round 2
// 6854.221 us; speedup vs baseline: 1.3953x; 1.3953x over previous
//
#include <hip/hip_runtime.h>
#include <math.h>

#define N 64
#define LDA 65          // A: +1 pad, bank(A[i][j]) = (i+j)%32 -> near-uniform for scattered pair access
#define SWEEPS 8

__device__ __forceinline__ void get_pair(int r, int k, int& p, int& q) {
    // Circle-method tournament: round r in [0,63), pair k in [0,32)
    if (k == 0) { p = 63; q = r; }
    else {
        p = r + k; if (p >= 63) p -= 63;
        q = r - k; if (q < 0)  q += 63;
    }
}

__global__ __launch_bounds__(256)
void logeig_kernel(const float* __restrict__ P, float* __restrict__ Out) {
    __shared__ float As[N * LDA];          // A, padded stride 65 (scattered b32 access)
    __shared__ float Ut[N * N];            // U^T, stride 64 (vectorized b128 row access)
    __shared__ float2 rcs[32];             // (c, s) per pair
    __shared__ float lw[N];

    const int t = threadIdx.x;
    const int bid = blockIdx.x;
    const float* A0 = P + (size_t)bid * (N * N);
    float* O = Out + (size_t)bid * (N * N);

    // ---- Load A (coalesced float4) into padded As; init Ut = I (stride 64) ----
    const float4* A4 = (const float4*)A0;
    float4* U4 = (float4*)Ut;
    #pragma unroll
    for (int kk = 0; kk < 4; ++kk) {
        int f = t + kk * 256;            // float4 index in [0,1024)
        float4 v = A4[f];
        int e = f * 4;
        int row = e >> 6;
        int col = e & 63;
        float* ap = &As[row * LDA + col];
        ap[0] = v.x; ap[1] = v.y; ap[2] = v.z; ap[3] = v.w;
        float4 id;
        id.x = (col + 0 == row) ? 1.f : 0.f;
        id.y = (col + 1 == row) ? 1.f : 0.f;
        id.z = (col + 2 == row) ? 1.f : 0.f;
        id.w = (col + 3 == row) ? 1.f : 0.f;
        U4[f] = id;
    }
    __syncthreads();

    // ---- Jacobi sweeps ----
    for (int sweep = 0; sweep < SWEEPS; ++sweep) {
        for (int r = 0; r < 63; ++r) {
            // Phase 1: rotation params for 32 pairs
            if (t < 32) {
                int p, q; get_pair(r, t, p, q);
                float app = As[p * LDA + p];
                float aqq = As[q * LDA + q];
                float apq = As[p * LDA + q];
                float c = 1.f, s = 0.f;
                if (fabsf(apq) > 1e-30f) {
                    float tau = (aqq - app) / (2.f * apq);
                    float tt = 1.f / (fabsf(tau) + sqrtf(1.f + tau * tau));
                    if (tau < 0.f) tt = -tt;
                    c = rsqrtf(1.f + tt * tt);
                    s = tt * c;
                }
                rcs[t] = make_float2(c, s);
            }
            __syncthreads();

            // Phase 2a: fused 2x2-block update of A (A <- J^T A J), in place, b32.
            {
                int ki = t & 31;
                int p1, q1; get_pair(r, ki, p1, q1);
                float2 cs1 = rcs[ki];
                float c1 = cs1.x, s1 = cs1.y;
                int p1r = p1 * LDA, q1r = q1 * LDA;
                #pragma unroll
                for (int jj = 0; jj < 4; ++jj) {
                    int kj = (t >> 5) + 8 * jj;
                    int p2, q2; get_pair(r, kj, p2, q2);
                    float2 cs2 = rcs[kj];
                    float c2 = cs2.x, s2 = cs2.y;
                    float m00 = As[p1r + p2];
                    float m01 = As[p1r + q2];
                    float m10 = As[q1r + p2];
                    float m11 = As[q1r + q2];
                    float n00 = c2 * m00 - s2 * m01;
                    float n01 = s2 * m00 + c2 * m01;
                    float n10 = c2 * m10 - s2 * m11;
                    float n11 = s2 * m10 + c2 * m11;
                    As[p1r + p2] = c1 * n00 - s1 * n10;
                    As[p1r + q2] = c1 * n01 - s1 * n11;
                    As[q1r + p2] = s1 * n00 + c1 * n10;
                    As[q1r + q2] = s1 * n01 + c1 * n11;
                }
            }
            // Phase 2b: Ut <- J^T Ut (row rotations), vectorized b128, conflict-free.
            // 16 lanes sweep one row contiguously: lanes (k=t>>4, g4=t&15) cover
            // words 4*g4 .. 4*g4+3 -> consecutive lanes, consecutive addresses.
            {
                int g4 = t & 15;
                #pragma unroll
                for (int kk = 0; kk < 2; ++kk) {
                    int k = (t >> 4) + 16 * kk;
                    int p, q; get_pair(r, k, p, q);
                    float2 cs = rcs[k];
                    float c = cs.x, s = cs.y;
                    float4* rp = (float4*)&Ut[p * N + 4 * g4];
                    float4* rq = (float4*)&Ut[q * N + 4 * g4];
                    float4 up = *rp;
                    float4 uq = *rq;
                    float4 np, nq;
                    np.x = c * up.x - s * uq.x;  nq.x = s * up.x + c * uq.x;
                    np.y = c * up.y - s * uq.y;  nq.y = s * up.y + c * uq.y;
                    np.z = c * up.z - s * uq.z;  nq.z = s * up.z + c * uq.z;
                    np.w = c * up.w - s * uq.w;  nq.w = s * up.w + c * uq.w;
                    *rp = np;
                    *rq = nq;
                }
            }
            __syncthreads();
        }
    }

    // ---- log of eigenvalues (diagonal of As) ----
    if (t < 64) lw[t] = logf(fmaxf(As[t * LDA + t], 1e-30f));
    __syncthreads();

    // ---- X = U diag(lw) U^T = sum_k Ut[k][:]^T lw[k] Ut[k][:]; 4x4 tile/thread ----
    {
        int ti = t >> 4;
        int tj = t & 15;
        float acc[4][4];
        #pragma unroll
        for (int a = 0; a < 4; ++a)
            #pragma unroll
            for (int b = 0; b < 4; ++b) acc[a][b] = 0.f;

        for (int k = 0; k < N; ++k) {
            float w = lw[k];
            float4 ui = *(const float4*)&Ut[k * N + 4 * ti];   // broadcast across tj
            float4 uj = *(const float4*)&Ut[k * N + 4 * tj];   // 2-way, free
            uj.x *= w; uj.y *= w; uj.z *= w; uj.w *= w;
            float ua[4] = {ui.x, ui.y, ui.z, ui.w};
            float ub[4] = {uj.x, uj.y, uj.z, uj.w};
            #pragma unroll
            for (int a = 0; a < 4; ++a)
                #pragma unroll
                for (int b = 0; b < 4; ++b)
                    acc[a][b] = fmaf(ua[a], ub[b], acc[a][b]);
        }
        #pragma unroll
        for (int a = 0; a < 4; ++a) {
            float4 vout = make_float4(acc[a][0], acc[a][1], acc[a][2], acc[a][3]);
            ((float4*)O)[(4 * ti + a) * 16 + tj] = vout;
        }
    }
}

extern "C" void kernel_launch(void* const* d_in, const int* in_sizes, int n_in,
                              void* d_out, int out_size, void* d_ws, size_t ws_size,
                              hipStream_t stream) {
    const float* P = (const float*)d_in[0];
    float* Out = (float*)d_out;
    int nmat = in_sizes[0] / (N * N);    // 8192
    logeig_kernel<<<dim3(nmat), dim3(256), 0, stream>>>(P, Out);
}